// Round 1
// baseline (243.549 us; speedup 1.0000x reference)
//
#include <hip/hip_runtime.h>

// ---------------------------------------------------------------------------
// SelfAttention: B=4, S=2048, D=1024, fp32 in/out, causal, no 1/sqrt(d).
// fp16 MFMA (16x16x32), fp32 accumulate, fp32 softmax.
//
// R9 = R8 + QKV GEMM rewritten as 256x256-tile 8-phase pipelined kernel
// (qkv256): BK=64, 8 waves (2Mx4N), 512 thr, 128 KiB LDS double-buffer,
// raw s_barrier (no vmcnt drain), counted s_waitcnt vmcnt(8) at even-phase
// ends (T4), s_setprio around MFMA clusters (T5), R8's XOR chunk swizzle
// for staging + fragment reads (T2, 0 bank conflicts). Schedule: per
// iteration 2 K-tiles / 8 phases; each phase stages one 16 KiB region with
// >=4-phase distance to first read. Scores/softmax/PV unchanged.
//
// ws layout (MiB):
//   [0,32)    Q,K fp16 slabs; later P fp16 overlays (after scores read Q,K)
//   [32,48)   Vt fp16 (b,e,s) — written by QKV epilogue
//   [48,112)  S fp32 (4x2048x2048)
//   [48,64)   x_h fp16      (over S; dead before S written)
//   [64,70)   Wh  fp16 [3072,1024] (over S; dead before S written)
// ---------------------------------------------------------------------------

typedef _Float16 h8 __attribute__((ext_vector_type(8)));
typedef _Float16 h4 __attribute__((ext_vector_type(4)));
typedef float f32x4 __attribute__((ext_vector_type(4)));

#define BM 128
#define BN 128

__device__ __forceinline__ void gl_lds16(const _Float16* g, _Float16* l) {
    __builtin_amdgcn_global_load_lds(
        (const __attribute__((address_space(1))) void*)g,
        (__attribute__((address_space(3))) void*)l, 16, 0, 0);
}

// ---------------------------------------------------------------------------
// QKV 256x256 8-phase kernel. A = x_h [8192][1024], B = Wh [3072][1024],
// C = QKV slabs (Q,K row-major [8192][1024] each; V transposed (b,e,s)).
//
// LDS map (halves): buffer d at d*32768; A at +0 (s0:+0, s1:+8192),
// B at +16384 (s0:+16384, s1:+24576). Region = 256 rows x 32 halves =
// 16 chunks x 1KB; wave wv stages chunks {wv, wv+8} (2 gl_lds/thread).
// Within chunk: lane l -> row l>>2, slot l&3; slot holds logical k-group
// (l&3)^((l>>3)&3); reads undo via sg = (qd ^ ((la>>1)&3))*8.
//
// Phase schedule per iteration (tiles K2i->buf0, K2i+1->buf1 already live):
//   P1: rd buf0(h0,s0)  stage A(K2i+1,s1)->buf1    P5: rd buf1(h0,s0)  stage A(K2i+2,s1)->buf0
//   P2: rd buf0(h1,s0)  stage B(K2i+1,s1) vm(8)    P6: rd buf1(h1,s0)  stage B(K2i+2,s1) vm(8)
//   P3: rd buf0(h0,s1)  stage A(K2i+2,s0)->buf0    P7: rd buf1(h0,s1)  stage A(K2i+3,s0)->buf1
//   P4: rd buf0(h1,s1)  stage B(K2i+2,s0) vm(8)    P8: rd buf1(h1,s1)  stage B(K2i+3,s0) vm(8)
// vmcnt(8) keeps 4 stage-ops (8 loads) in flight; each forces exactly the
// regions the following odd phase reads. Last iteration peeled: stages only
// K15 s1 at P1/P2; waits tighten 8 -> 4 -> 0.
// ---------------------------------------------------------------------------

#define BARX do { asm volatile("" ::: "memory"); __builtin_amdgcn_s_barrier(); \
                  asm volatile("" ::: "memory"); } while (0)
#define VMW(n) asm volatile("s_waitcnt vmcnt(" #n ")" ::: "memory")

#define LDA4(reg, h) do { _Pragma("unroll") \
    for (int i = 0; i < 4; i++) \
        af[i] = *(const h8*)&sm[(reg) + (wmr + (h) * 64 + i * 16 + la) * 32 + sg]; } while (0)

#define LDB4(reg) do { _Pragma("unroll") \
    for (int j = 0; j < 4; j++) \
        bf[j] = *(const h8*)&sm[(reg) + (wnr + j * 16 + la) * 32 + sg]; } while (0)

#define MMP(h) do { __builtin_amdgcn_s_setprio(1); _Pragma("unroll") \
    for (int i = 0; i < 4; i++) { _Pragma("unroll") \
        for (int j = 0; j < 4; j++) \
            acc[(h) * 4 + i][j] = __builtin_amdgcn_mfma_f32_16x16x32_f16( \
                af[i], bf[j], acc[(h) * 4 + i][j], 0, 0, 0); } \
    __builtin_amdgcn_s_setprio(0); } while (0)

#define STG(gp, off, ldsoff) do { \
    gl_lds16((gp) + rA1 + (off), lbase + (ldsoff)); \
    gl_lds16((gp) + rA2 + (off), lbase + (ldsoff) + 4096); } while (0)

__global__ __launch_bounds__(512, 2) void qkv256(
    const _Float16* __restrict__ A, const _Float16* __restrict__ B,
    _Float16* __restrict__ C)
{
    __shared__ __align__(16) _Float16 sm[65536];   // 128 KiB

    // XCD-bijective swizzle (384 % 8 == 0)
    const int bid = blockIdx.x;
    const int wg = (bid & 7) * 48 + (bid >> 3);
    const int by = wg / 12, bx = wg % 12;
    const int m0 = by * 256, n0 = bx * 256;

    const int tid = threadIdx.x;
    const int l = tid & 63;
    const int wv = tid >> 6;

    // staging addressing (R8 scheme): lane l -> row l>>2, logical k-group gsrc
    const int lr = l >> 2;
    const int gsrc = (l & 3) ^ ((l >> 3) & 3);
    const _Float16* gA = A + (size_t)(m0 + lr) * 1024 + gsrc * 8;
    const _Float16* gB = B + (size_t)(n0 + lr) * 1024 + gsrc * 8;
    const size_t rA1 = (size_t)(wv * 16) * 1024;        // chunk wv
    const size_t rA2 = (size_t)((wv + 8) * 16) * 1024;  // chunk wv+8
    _Float16* lbase = sm + wv * 512;

    // fragment addressing
    const int la = l & 15, qd = l >> 4;
    const int sg = (qd ^ ((la >> 1) & 3)) * 8;
    const int wmr = (wv >> 2) * 128;   // wave rows (M): 2 row-groups
    const int wnr = (wv & 3) * 64;     // wave cols (N): 4 col-groups

    f32x4 acc[8][4];
    #pragma unroll
    for (int i = 0; i < 8; i++)
        #pragma unroll
        for (int j = 0; j < 4; j++)
            acc[i][j] = (f32x4){0.f, 0.f, 0.f, 0.f};

    // prologue: K0 (buf0) full + K1 (buf1) s0; then allow 8 outstanding
    STG(gA, 0,  0);        // K0 A s0
    STG(gB, 0,  16384);    // K0 B s0
    STG(gA, 32, 8192);     // K0 A s1
    STG(gB, 32, 24576);    // K0 B s1
    STG(gA, 64, 32768);    // K1 A s0
    STG(gB, 64, 49152);    // K1 B s0
    VMW(8);
    BARX;

    #pragma unroll 1
    for (int it = 0; it < 7; ++it) {
        h8 af[4], bf[4];
        LDB4(16384); LDA4(0, 0);      STG(gA, 96, 40960);  BARX; MMP(0); BARX;
        LDA4(0, 1);                   STG(gB, 96, 57344);  BARX; MMP(1); VMW(8); BARX;
        LDB4(24576); LDA4(8192, 0);   STG(gA, 128, 0);     BARX; MMP(0); BARX;
        LDA4(8192, 1);                STG(gB, 128, 16384); BARX; MMP(1); VMW(8); BARX;
        LDB4(49152); LDA4(32768, 0);  STG(gA, 160, 8192);  BARX; MMP(0); BARX;
        LDA4(32768, 1);               STG(gB, 160, 24576); BARX; MMP(1); VMW(8); BARX;
        LDB4(57344); LDA4(40960, 0);  STG(gA, 192, 32768); BARX; MMP(0); BARX;
        LDA4(40960, 1);               STG(gB, 192, 49152); BARX; MMP(1); VMW(8); BARX;
        gA += 128; gB += 128;
    }
    {   // peeled last iteration (K14, K15): only K15 s1 still to stage
        h8 af[4], bf[4];
        LDB4(16384); LDA4(0, 0);      STG(gA, 96, 40960);  BARX; MMP(0); BARX;
        LDA4(0, 1);                   STG(gB, 96, 57344);  BARX; MMP(1); VMW(8); BARX;
        LDB4(24576); LDA4(8192, 0);                        BARX; MMP(0); BARX;
        LDA4(8192, 1);                                     BARX; MMP(1); VMW(4); BARX;
        LDB4(49152); LDA4(32768, 0);                       BARX; MMP(0); BARX;
        LDA4(32768, 1);                                    BARX; MMP(1); VMW(0); BARX;
        LDB4(57344); LDA4(40960, 0);                       BARX; MMP(0); BARX;
        LDA4(40960, 1);                                    BARX; MMP(1); BARX;
    }

    // epilogue: D layout col=la, row=qd*4+rr (verified R8 mapping)
    if (bx < 8) {
        // Q/K slabs, row-major [s][e] within slab, ld 1024
        #pragma unroll
        for (int i = 0; i < 8; i++) {
            const int m = m0 + wmr + i * 16 + qd * 4;
            #pragma unroll
            for (int j = 0; j < 4; j++) {
                const int col = n0 + wnr + j * 16 + la;
                const size_t base = (size_t)(col >> 10) * 8388608 + (col & 1023);
                #pragma unroll
                for (int rr = 0; rr < 4; rr++)
                    C[base + (size_t)(m + rr) * 1024] = (_Float16)acc[i][j][rr];
            }
        }
    } else {
        // V slab stored transposed: Vt (b, e, s); rr -> s contiguous
        _Float16* Vt = C + (size_t)2 * 8388608;
        #pragma unroll
        for (int i = 0; i < 8; i++) {
            const int m = m0 + wmr + i * 16 + qd * 4;
            const int b = m >> 11;
            const int sl = m & 2047;
            _Float16* Vb = Vt + (size_t)b * 2097152 + sl;
            #pragma unroll
            for (int j = 0; j < 4; j++) {
                const int e = n0 - 2048 + wnr + j * 16 + la;
                h4 vv = { (_Float16)acc[i][j][0], (_Float16)acc[i][j][1],
                          (_Float16)acc[i][j][2], (_Float16)acc[i][j][3] };
                *(h4*)(Vb + (size_t)e * 2048) = vv;
            }
        }
    }
}

// ---------------------------------------------------------------------------
// NT GEMM (R8 structure) kept for scores (SWZ=2) and PV (SWZ=3).
// ---------------------------------------------------------------------------
template<int SWZ, int OM, bool KLIM>
__global__ __launch_bounds__(256) void gemm_nt(
    const _Float16* __restrict__ A, const _Float16* __restrict__ B,
    void* __restrict__ Cp, int N, int K,
    size_t sAz, size_t sBz, size_t sCz)
{
    __shared__ __align__(16) char smem[32768];
    _Float16* As = (_Float16*)smem;              // 2 x 4096 halves (k-stages)
    _Float16* Bs = (_Float16*)(smem + 16384);    // 2 x 4096 halves

    int bx, by;
    if (SWZ == 1) {
        const int r = blockIdx.x & 7, q2 = blockIdx.x >> 3;
        bx = q2 >> 3;
        by = ((q2 & 7) << 3) | r;
    } else if (SWZ == 2) {
        const int r = blockIdx.x & 7, g = blockIdx.x >> 3;   // g in 0..16
        if (g <= r) { by = r;      bx = g; }
        else        { by = 15 - r; bx = g - (r + 1); }
    } else {                                      // SWZ == 3
        const int r = blockIdx.x & 7, g = blockIdx.x >> 3;   // g in 0..15
        by = (g & 1) ? (15 - r) : r;
        bx = g >> 1;
    }

    const int tid  = threadIdx.x;
    const int lane = tid & 63;
    const int wv   = tid >> 6;
    const int m0 = by * BM, n0 = bx * BN;
    const size_t z = blockIdx.z;

    const int lr = lane >> 2;
    const int lc = ((lane & 3) ^ ((lane >> 3) & 3)) * 8;
    const _Float16* pA0 = A + z * sAz + (size_t)(m0 + wv * 16 + lr) * K + lc;
    const _Float16* pA1 = pA0 + (size_t)64 * K;
    const _Float16* pB0 = B + z * sBz + (size_t)(n0 + wv * 16 + lr) * K + lc;
    const _Float16* pB1 = pB0 + (size_t)64 * K;
    _Float16* lA0 = As + wv * 512;
    _Float16* lA1 = As + (wv + 4) * 512;
    _Float16* lB0 = Bs + wv * 512;
    _Float16* lB1 = Bs + (wv + 4) * 512;

    const int la = lane & 15;
    const int qd = lane >> 4;
    const int wm = (wv >> 1) * 64;
    const int wn = (wv & 1) * 64;
    const int sg = (qd ^ ((la >> 1) & 3)) * 8;

    f32x4 acc[4][4];
    #pragma unroll
    for (int i = 0; i < 4; i++)
        #pragma unroll
        for (int j = 0; j < 4; j++)
            acc[i][j] = (f32x4){0.f, 0.f, 0.f, 0.f};

    const int kEnd = KLIM ? (m0 + BM) : K;

    for (int k0 = 0; k0 < kEnd; k0 += 64) {
        gl_lds16(pA0,      lA0);
        gl_lds16(pA1,      lA1);
        gl_lds16(pB0,      lB0);
        gl_lds16(pB1,      lB1);
        gl_lds16(pA0 + 32, lA0 + 4096);
        gl_lds16(pA1 + 32, lA1 + 4096);
        gl_lds16(pB0 + 32, lB0 + 4096);
        gl_lds16(pB1 + 32, lB1 + 4096);
        pA0 += 64; pA1 += 64; pB0 += 64; pB1 += 64;
        __syncthreads();

        #pragma unroll
        for (int s = 0; s < 2; s++) {
            h8 af[4], bf[4];
            #pragma unroll
            for (int i = 0; i < 4; i++)
                af[i] = *(const h8*)&As[s * 4096 + (wm + i * 16 + la) * 32 + sg];
            #pragma unroll
            for (int i = 0; i < 4; i++)
                bf[i] = *(const h8*)&Bs[s * 4096 + (wn + i * 16 + la) * 32 + sg];
            #pragma unroll
            for (int i = 0; i < 4; i++)
                #pragma unroll
                for (int j = 0; j < 4; j++)
                    acc[i][j] = __builtin_amdgcn_mfma_f32_16x16x32_f16(af[i], bf[j], acc[i][j], 0, 0, 0);
        }
        __syncthreads();
    }

    if (OM == 2) {
        _Float16* C = (_Float16*)Cp;
        if (n0 < 2048) {
            #pragma unroll
            for (int i = 0; i < 4; i++)
                #pragma unroll
                for (int j = 0; j < 4; j++) {
                    const int col  = n0 + wn + j * 16 + la;
                    const size_t base = (size_t)(col >> 10) * 8388608 + (col & 1023);
                    #pragma unroll
                    for (int rr = 0; rr < 4; rr++)
                        C[base + (size_t)(m0 + wm + i * 16 + qd * 4 + rr) * 1024] =
                            (_Float16)acc[i][j][rr];
                }
        } else {
            _Float16* Vt = C + (size_t)2 * 8388608;
            #pragma unroll
            for (int i = 0; i < 4; i++) {
                const int m  = m0 + wm + i * 16 + qd * 4;
                const int b  = m >> 11;
                const int sl = m & 2047;
                _Float16* Vb = Vt + (size_t)b * 2097152 + sl;
                #pragma unroll
                for (int j = 0; j < 4; j++) {
                    const int e = n0 - 2048 + wn + j * 16 + la;
                    h4 vv = { (_Float16)acc[i][j][0], (_Float16)acc[i][j][1],
                              (_Float16)acc[i][j][2], (_Float16)acc[i][j][3] };
                    *(h4*)(Vb + (size_t)e * 2048) = vv;
                }
            }
        }
    } else {
        float* C = (float*)Cp + z * sCz;
        #pragma unroll
        for (int i = 0; i < 4; i++)
            #pragma unroll
            for (int j = 0; j < 4; j++)
                #pragma unroll
                for (int rr = 0; rr < 4; rr++)
                    C[(size_t)(m0 + wm + i * 16 + qd * 4 + rr) * N + (n0 + wn + j * 16 + la)] =
                        acc[i][j][rr];
    }
}

// fused fp32->fp16: blocks [0,4096) convert x (8M), [4096,5632) convert W (3x1M)
__global__ __launch_bounds__(256) void cvt_all(
    const float* __restrict__ x, const float* __restrict__ Wq,
    const float* __restrict__ Wk, const float* __restrict__ Wv,
    _Float16* __restrict__ x_h, _Float16* __restrict__ Wh)
{
    const int bid = blockIdx.x;
    const float* src; _Float16* dst; size_t off;
    if (bid < 4096) {
        src = x; dst = x_h; off = (size_t)bid * 2048;
    } else {
        const int b2 = bid - 4096;
        const int w = b2 >> 9;
        src = (w == 0) ? Wq : ((w == 1) ? Wk : Wv);
        dst = Wh + (size_t)w * 1048576;
        off = (size_t)(b2 & 511) * 2048;
    }
    const size_t i = off + (size_t)threadIdx.x * 8;
    float4 a = *(const float4*)(src + i);
    float4 b = *(const float4*)(src + i + 4);
    h8 o = { (_Float16)a.x, (_Float16)a.y, (_Float16)a.z, (_Float16)a.w,
             (_Float16)b.x, (_Float16)b.y, (_Float16)b.z, (_Float16)b.w };
    *(h8*)(dst + i) = o;
}

// causal row softmax: S fp32 -> P fp16. Thread t owns cols 8t..8t+7.
__global__ __launch_bounds__(256) void softmax_causal(const float* __restrict__ S,
                                                      _Float16* __restrict__ P)
{
    const int idx = blockIdx.x;          // 0..8191
    const int q = idx & 2047;
    const float* Srow = S + (size_t)idx * 2048;
    _Float16* Prow = P + (size_t)idx * 2048;
    const int t = threadIdx.x;
    const int k0 = t * 8;
    const int lane = t & 63, wv = t >> 6;
    __shared__ float red[4];

    float v[8];
    const bool any = (k0 <= q);
    if (any) {
        float4 a = *(const float4*)(Srow + k0);
        float4 b = *(const float4*)(Srow + k0 + 4);
        v[0] = a.x; v[1] = a.y; v[2] = a.z; v[3] = a.w;
        v[4] = b.x; v[5] = b.y; v[6] = b.z; v[7] = b.w;
    }
    float mx = -3.4e38f;
    #pragma unroll
    for (int j = 0; j < 8; j++)
        if (any && k0 + j <= q) mx = fmaxf(mx, v[j]);
    #pragma unroll
    for (int o = 32; o > 0; o >>= 1) mx = fmaxf(mx, __shfl_down(mx, o, 64));
    if (lane == 0) red[wv] = mx;
    __syncthreads();
    const float mall = fmaxf(fmaxf(red[0], red[1]), fmaxf(red[2], red[3]));
    __syncthreads();

    float sum = 0.f;
    #pragma unroll
    for (int j = 0; j < 8; j++) {
        float e = (any && k0 + j <= q) ? __expf(v[j] - mall) : 0.f;
        v[j] = e;
        sum += e;
    }
    #pragma unroll
    for (int o = 32; o > 0; o >>= 1) sum += __shfl_down(sum, o, 64);
    if (lane == 0) red[wv] = sum;
    __syncthreads();
    const float inv = 1.f / (red[0] + red[1] + red[2] + red[3]);

    const int kceil = ((q >> 7) + 1) << 7;       // PV reads cols < kceil
    if (k0 < kceil) {
        h8 o = { (_Float16)(v[0] * inv), (_Float16)(v[1] * inv),
                 (_Float16)(v[2] * inv), (_Float16)(v[3] * inv),
                 (_Float16)(v[4] * inv), (_Float16)(v[5] * inv),
                 (_Float16)(v[6] * inv), (_Float16)(v[7] * inv) };
        *(h8*)(Prow + k0) = o;
    }
}

extern "C" void kernel_launch(void* const* d_in, const int* in_sizes, int n_in,
                              void* d_out, int out_size, void* d_ws, size_t ws_size,
                              hipStream_t stream) {
    const float* x  = (const float*)d_in[0];
    const float* Wq = (const float*)d_in[1];
    const float* Wk = (const float*)d_in[2];
    const float* Wv = (const float*)d_in[3];
    float* out = (float*)d_out;

    const size_t MiB = 1024 * 1024;
    char* ws = (char*)d_ws;
    _Float16* QKVh = (_Float16*)ws;                     // Q,K slabs + Vt at slab 2
    _Float16* Vt   = QKVh + (size_t)2 * 8388608;        // [32,48) MiB, (b,e,s)
    float*    S    = (float*)(ws + 48 * MiB);           // 64 MiB
    _Float16* x_h  = (_Float16*)(ws + 48 * MiB);        // 16 MiB (over S)
    _Float16* Wh   = (_Float16*)(ws + 64 * MiB);        // 6 MiB  (over S)
    _Float16* P    = (_Float16*)ws;                     // 32 MiB (over Q,K)

    const dim3 blk(256);

    // 0) fp32 -> fp16 conversions (one dispatch)
    cvt_all<<<dim3(5632), blk, 0, stream>>>(x, Wq, Wk, Wv, x_h, Wh);

    // 1) QKV fused, 256x256 8-phase: M=8192, N=3072; Q,K slabs + Vt(b,e,s)
    qkv256<<<dim3(384), dim3(512), 0, stream>>>(x_h, Wh, QKVh);

    // 2) scores: balanced lower-triangle decode, 136 tiles/batch
    gemm_nt<2, 0, false><<<dim3(136, 1, 4), blk, 0, stream>>>(
        QKVh, QKVh + 8388608, S, 2048, 1024,
        (size_t)2097152, (size_t)2097152, (size_t)4194304);

    // 3) causal softmax rows -> P fp16 (over Q,K)
    softmax_causal<<<dim3(4 * 2048), blk, 0, stream>>>(S, P);

    // 4) out = P @ Vt^T, fp32 out, K clipped at m0+128, residue swizzle
    gemm_nt<3, 0, true><<<dim3(128, 1, 4), blk, 0, stream>>>(
        P, Vt, out, 1024, 2048,
        (size_t)4194304, (size_t)2097152, (size_t)2097152);
}

// Round 2
// 237.386 us; speedup vs baseline: 1.0260x; 1.0260x over previous
//
#include <hip/hip_runtime.h>

// ---------------------------------------------------------------------------
// SelfAttention: B=4, S=2048, D=1024, fp32 in/out, causal, no 1/sqrt(d).
// fp16 MFMA (16x16x32), fp32 accumulate, fp32 softmax.
//
// R10 = R9 with QKV rebuilt as qkv192:
//  - 256x192 tiles -> grid 32x16 = 512 blocks = EXACTLY 2 rounds at 1
//    block/CU (R9's 384 blocks = 1.5 rounds wasted ~25% machine).
//  - dense-line staging: regions are full-K (BK=64 = one 128B line/row);
//    each global_load_lds covers 8 rows x 128B DENSE (R9 gathered 16
//    scattered 64B half-lines -> 2x L2 transactions, the per-phase stall).
//    Bank swizzle moved to intra-row seg-XOR sigma(r)=r&7 applied on the
//    GLOBAL source (LDS linear), undone at fragment read:
//    phys_seg = (s*4+qd) ^ (la&7); verified 2-pass/16-lane = conflict-free.
//  - full-K regions force M-split schedule: A triple-buffer (3x32KB) +
//    B double-buffer (2x24KB) = 144 KiB LDS. 4 phases/window (=K-tile),
//    one 8-16KB region staged per phase, vmcnt(4) once per window.
//    Steady in-flight = 11 ops/wave; each VMW(4) retires exactly the
//    A(n+1)+B(n+1) regions read in the next window (distances 2-5 phases).
//
// ws layout (MiB):
//   [0,32)    Q,K fp16 slabs; later P fp16 overlays (after scores read Q,K)
//   [32,48)   Vt fp16 (b,e,s) — written by QKV epilogue
//   [48,112)  S fp32 (4x2048x2048)
//   [48,64)   x_h fp16      (over S; dead before S written)
//   [64,70)   Wh  fp16 [3072,1024] (over S; dead before S written)
// ---------------------------------------------------------------------------

typedef _Float16 h8 __attribute__((ext_vector_type(8)));
typedef _Float16 h4 __attribute__((ext_vector_type(4)));
typedef float f32x4 __attribute__((ext_vector_type(4)));

#define BM 128
#define BN 128

__device__ __forceinline__ void gl_lds16(const _Float16* g, _Float16* l) {
    __builtin_amdgcn_global_load_lds(
        (const __attribute__((address_space(1))) void*)g,
        (__attribute__((address_space(3))) void*)l, 16, 0, 0);
}

#define BARX do { asm volatile("" ::: "memory"); __builtin_amdgcn_s_barrier(); \
                  asm volatile("" ::: "memory"); } while (0)
#define VMW(n) asm volatile("s_waitcnt vmcnt(" #n ")" ::: "memory")

// ---------------------------------------------------------------------------
// qkv192: A = x_h [8192][1024], B = Wh [3072][1024], C = QKV slabs.
// 8 waves 2Mx4N, per-wave 128x48 (8 M-frags x 3 N-frags), acc[8][3].
//
// LDS (halves): Ab0@0 Ab1@16384 Ab2@32768 (each [256][64]);
//               Bb0@49152 Bb1@61440 (each [192][64]). Total 73728 h = 144KB.
// Region layout: row r at r*64, seg s_lds at +s_lds*8; (r,s_lds) holds
// GLOBAL seg s_lds ^ (r&7) (sigma pre-applied at the global source).
// Staging op = 1KB = 8 rows dense: lane l -> row +(l>>3), src seg
// (l&7)^((l>>3)&7) -> each row's 8 lanes cover one dense 128B line.
//
// Window n (4 phases), reads A(n) in Ab[n%3], B(n) in Bb[n%2]:
//   Ph0: bf(s0)+af(h0,s0); stage B(n+1).lo(2)   | BAR; 12 MFMA; BAR
//   Ph1: af(h1,s0);        stage B(n+1).hi(1)   | BAR; 12 MFMA; BAR
//   Ph2: bf(s1)+af(h0,s1); stage A(n+2).lo(2)   | BAR; 12 MFMA; BAR
//   Ph3: af(h1,s1);        stage A(n+2).hi(2)   | BAR; 12 MFMA; VMW(4); BAR
// VMW(4): outstanding = A(n+1).4 + B(n+1).3 + A(n+2).4 = 11 -> forces
// A(n+1)+B(n+1) (read next window), leaves A(n+2) in flight.
// ---------------------------------------------------------------------------

#define SA_LO(gp, ab) do { gl_lds16((gp),          (ab) + wv * 1024); \
                           gl_lds16((gp) + 8192,   (ab) + wv * 1024 + 512); } while (0)
#define SA_HI(gp, ab) do { gl_lds16((gp) + 131072, (ab) + wv * 1024 + 8192); \
                           gl_lds16((gp) + 139264, (ab) + wv * 1024 + 8704); } while (0)
#define SB_LO(gp, bb) do { gl_lds16((gp),          (bb) + wv * 1024); \
                           gl_lds16((gp) + 8192,   (bb) + wv * 1024 + 512); } while (0)
#define SB_HI(gp2, bb)     gl_lds16((gp2),         (bb) + 8192 + wv * 512)

#define LDA(ab, h, ap) do { _Pragma("unroll") \
    for (int i = 0; i < 4; i++) \
        af[i] = *(const h8*)&(ab)[abase + (h) * 4096 + i * 1024 + (ap)]; } while (0)
#define LDB(bb, ap) do { _Pragma("unroll") \
    for (int j = 0; j < 3; j++) \
        bf[j] = *(const h8*)&(bb)[bbase + j * 1024 + (ap)]; } while (0)

#define MMP(h) do { __builtin_amdgcn_s_setprio(1); _Pragma("unroll") \
    for (int i = 0; i < 4; i++) { _Pragma("unroll") \
        for (int j = 0; j < 3; j++) \
            acc[(h) * 4 + i][j] = __builtin_amdgcn_mfma_f32_16x16x32_f16( \
                af[i], bf[j], acc[(h) * 4 + i][j], 0, 0, 0); } \
    __builtin_amdgcn_s_setprio(0); } while (0)

__global__ __launch_bounds__(512, 2) void qkv192(
    const _Float16* __restrict__ A, const _Float16* __restrict__ B,
    _Float16* __restrict__ C)
{
    __shared__ __align__(16) _Float16 sm[73728];   // 144 KiB

    // XCD-bijective swizzle (512 % 8 == 0)
    const int bid = blockIdx.x;
    const int wg = (bid & 7) * 64 + (bid >> 3);
    const int by = wg >> 4, bx = wg & 15;
    const int m0 = by * 256, n0 = bx * 192;

    const int tid = threadIdx.x;
    const int l = tid & 63;
    const int wv = tid >> 6;

    // staging addressing: lane l -> row +(l>>3), global seg (l&7)^((l>>3)&7)
    const int prow = wv * 16 + (l >> 3);
    const int pseg = ((l & 7) ^ ((l >> 3) & 7)) * 8;
    const _Float16* gA  = A + (size_t)(m0 + prow) * 1024 + pseg;
    const _Float16* gB  = B + (size_t)(n0 + prow) * 1024 + pseg;
    const _Float16* gB2 = B + (size_t)(n0 + 128 + wv * 8 + (l >> 3)) * 1024 + pseg;

    // fragment addressing
    const int la = l & 15, qd = l >> 4;
    const int wmr = (wv >> 2) * 128;            // 2 M row-groups
    const int wnr = (wv & 3) * 48;              // 4 N col-groups of 48
    const int ap0 = ((qd) ^ (la & 7)) * 8;      // k-step s=0 phys seg
    const int ap1 = ((4 + qd) ^ (la & 7)) * 8;  // k-step s=1 phys seg
    const int abase = (wmr + la) * 64;
    const int bbase = (wnr + la) * 64;

    _Float16* a0 = sm;
    _Float16* a1 = sm + 16384;
    _Float16* a2 = sm + 32768;
    _Float16* b0 = sm + 49152;
    _Float16* b1 = sm + 61440;

    f32x4 acc[8][3];
    #pragma unroll
    for (int i = 0; i < 8; i++)
        #pragma unroll
        for (int j = 0; j < 3; j++)
            acc[i][j] = (f32x4){0.f, 0.f, 0.f, 0.f};

    // prologue: A(0)->Ab0, B(0)->Bb0, A(1)->Ab1 (11 ops); force A(0)+B(0)
    SA_LO(gA, a0);      SA_HI(gA, a0);
    SB_LO(gB, b0);      SB_HI(gB2, b0);
    SA_LO(gA + 64, a1); SA_HI(gA + 64, a1);
    VMW(4);
    BARX;

    const _Float16* pA  = gA + 128;    // k-offset of A(2)
    const _Float16* pB  = gB + 64;     // k-offset of B(1)
    const _Float16* pB2 = gB2 + 64;

    #pragma unroll 1
    for (int n = 0; n < 14; ++n) {
        h8 af[4], bf[3];
        LDB(b0, ap0); LDA(a0, 0, ap0); SB_LO(pB, b1);  BARX; MMP(0); BARX;
        LDA(a0, 1, ap0);               SB_HI(pB2, b1); BARX; MMP(1); BARX;
        LDB(b0, ap1); LDA(a0, 0, ap1); SA_LO(pA, a2);  BARX; MMP(0); BARX;
        LDA(a0, 1, ap1);               SA_HI(pA, a2);  BARX; MMP(1); VMW(4); BARX;
        _Float16* t = a0; a0 = a1; a1 = a2; a2 = t;
        t = b0; b0 = b1; b1 = t;
        pA += 64; pB += 64; pB2 += 64;
    }
    {   // W14: stage only B(15); drain everything at end
        h8 af[4], bf[3];
        LDB(b0, ap0); LDA(a0, 0, ap0); SB_LO(pB, b1);  BARX; MMP(0); BARX;
        LDA(a0, 1, ap0);               SB_HI(pB2, b1); BARX; MMP(1); BARX;
        LDB(b0, ap1); LDA(a0, 0, ap1);                 BARX; MMP(0); BARX;
        LDA(a0, 1, ap1);                               BARX; MMP(1); VMW(0); BARX;
        _Float16* t = a0; a0 = a1; a1 = a2; a2 = t;
        t = b0; b0 = b1; b1 = t;
    }
    {   // W15: reads only
        h8 af[4], bf[3];
        LDB(b0, ap0); LDA(a0, 0, ap0); BARX; MMP(0); BARX;
        LDA(a0, 1, ap0);               BARX; MMP(1); BARX;
        LDB(b0, ap1); LDA(a0, 0, ap1); BARX; MMP(0); BARX;
        LDA(a0, 1, ap1);               BARX; MMP(1);
    }

    // epilogue: D layout col=la, row=qd*4+rr. Slab chosen per 16-aligned
    // frag column (tiles can straddle Q|K|V boundaries since 192∤1024).
    #pragma unroll
    for (int i = 0; i < 8; i++) {
        const int m = m0 + wmr + i * 16 + qd * 4;
        #pragma unroll
        for (int j = 0; j < 3; j++) {
            const int col16 = n0 + wnr + j * 16;
            const int slab = col16 >> 10;
            if (slab < 2) {
                // Q/K slabs, row-major [s][e] within slab, ld 1024
                const size_t base = (size_t)slab * 8388608 + (col16 & 1023) + la;
                #pragma unroll
                for (int rr = 0; rr < 4; rr++)
                    C[base + (size_t)(m + rr) * 1024] = (_Float16)acc[i][j][rr];
            } else {
                // V slab stored transposed: Vt (b, e, s); rr -> s contiguous
                _Float16* Vt = C + (size_t)2 * 8388608;
                const int e = col16 + la - 2048;
                const int b = m >> 11;
                const int sl = m & 2047;
                h4 vv = { (_Float16)acc[i][j][0], (_Float16)acc[i][j][1],
                          (_Float16)acc[i][j][2], (_Float16)acc[i][j][3] };
                *(h4*)(Vt + (size_t)b * 2097152 + (size_t)e * 2048 + sl) = vv;
            }
        }
    }
}

// ---------------------------------------------------------------------------
// NT GEMM (R8 structure) kept for scores (SWZ=2) and PV (SWZ=3).
// ---------------------------------------------------------------------------
template<int SWZ, int OM, bool KLIM>
__global__ __launch_bounds__(256) void gemm_nt(
    const _Float16* __restrict__ A, const _Float16* __restrict__ B,
    void* __restrict__ Cp, int N, int K,
    size_t sAz, size_t sBz, size_t sCz)
{
    __shared__ __align__(16) char smem[32768];
    _Float16* As = (_Float16*)smem;              // 2 x 4096 halves (k-stages)
    _Float16* Bs = (_Float16*)(smem + 16384);    // 2 x 4096 halves

    int bx, by;
    if (SWZ == 1) {
        const int r = blockIdx.x & 7, q2 = blockIdx.x >> 3;
        bx = q2 >> 3;
        by = ((q2 & 7) << 3) | r;
    } else if (SWZ == 2) {
        const int r = blockIdx.x & 7, g = blockIdx.x >> 3;   // g in 0..16
        if (g <= r) { by = r;      bx = g; }
        else        { by = 15 - r; bx = g - (r + 1); }
    } else {                                      // SWZ == 3
        const int r = blockIdx.x & 7, g = blockIdx.x >> 3;   // g in 0..15
        by = (g & 1) ? (15 - r) : r;
        bx = g >> 1;
    }

    const int tid  = threadIdx.x;
    const int lane = tid & 63;
    const int wv   = tid >> 6;
    const int m0 = by * BM, n0 = bx * BN;
    const size_t z = blockIdx.z;

    const int lr = lane >> 2;
    const int lc = ((lane & 3) ^ ((lane >> 3) & 3)) * 8;
    const _Float16* pA0 = A + z * sAz + (size_t)(m0 + wv * 16 + lr) * K + lc;
    const _Float16* pA1 = pA0 + (size_t)64 * K;
    const _Float16* pB0 = B + z * sBz + (size_t)(n0 + wv * 16 + lr) * K + lc;
    const _Float16* pB1 = pB0 + (size_t)64 * K;
    _Float16* lA0 = As + wv * 512;
    _Float16* lA1 = As + (wv + 4) * 512;
    _Float16* lB0 = Bs + wv * 512;
    _Float16* lB1 = Bs + (wv + 4) * 512;

    const int la = lane & 15;
    const int qd = lane >> 4;
    const int wm = (wv >> 1) * 64;
    const int wn = (wv & 1) * 64;
    const int sg = (qd ^ ((la >> 1) & 3)) * 8;

    f32x4 acc[4][4];
    #pragma unroll
    for (int i = 0; i < 4; i++)
        #pragma unroll
        for (int j = 0; j < 4; j++)
            acc[i][j] = (f32x4){0.f, 0.f, 0.f, 0.f};

    const int kEnd = KLIM ? (m0 + BM) : K;

    for (int k0 = 0; k0 < kEnd; k0 += 64) {
        gl_lds16(pA0,      lA0);
        gl_lds16(pA1,      lA1);
        gl_lds16(pB0,      lB0);
        gl_lds16(pB1,      lB1);
        gl_lds16(pA0 + 32, lA0 + 4096);
        gl_lds16(pA1 + 32, lA1 + 4096);
        gl_lds16(pB0 + 32, lB0 + 4096);
        gl_lds16(pB1 + 32, lB1 + 4096);
        pA0 += 64; pA1 += 64; pB0 += 64; pB1 += 64;
        __syncthreads();

        #pragma unroll
        for (int s = 0; s < 2; s++) {
            h8 af[4], bf[4];
            #pragma unroll
            for (int i = 0; i < 4; i++)
                af[i] = *(const h8*)&As[s * 4096 + (wm + i * 16 + la) * 32 + sg];
            #pragma unroll
            for (int i = 0; i < 4; i++)
                bf[i] = *(const h8*)&Bs[s * 4096 + (wn + i * 16 + la) * 32 + sg];
            #pragma unroll
            for (int i = 0; i < 4; i++)
                #pragma unroll
                for (int j = 0; j < 4; j++)
                    acc[i][j] = __builtin_amdgcn_mfma_f32_16x16x32_f16(af[i], bf[j], acc[i][j], 0, 0, 0);
        }
        __syncthreads();
    }

    if (OM == 2) {
        _Float16* C = (_Float16*)Cp;
        if (n0 < 2048) {
            #pragma unroll
            for (int i = 0; i < 4; i++)
                #pragma unroll
                for (int j = 0; j < 4; j++) {
                    const int col  = n0 + wn + j * 16 + la;
                    const size_t base = (size_t)(col >> 10) * 8388608 + (col & 1023);
                    #pragma unroll
                    for (int rr = 0; rr < 4; rr++)
                        C[base + (size_t)(m0 + wm + i * 16 + qd * 4 + rr) * 1024] =
                            (_Float16)acc[i][j][rr];
                }
        } else {
            _Float16* Vt = C + (size_t)2 * 8388608;
            #pragma unroll
            for (int i = 0; i < 4; i++) {
                const int m  = m0 + wm + i * 16 + qd * 4;
                const int b  = m >> 11;
                const int sl = m & 2047;
                _Float16* Vb = Vt + (size_t)b * 2097152 + sl;
                #pragma unroll
                for (int j = 0; j < 4; j++) {
                    const int e = n0 - 2048 + wn + j * 16 + la;
                    h4 vv = { (_Float16)acc[i][j][0], (_Float16)acc[i][j][1],
                              (_Float16)acc[i][j][2], (_Float16)acc[i][j][3] };
                    *(h4*)(Vb + (size_t)e * 2048) = vv;
                }
            }
        }
    } else {
        float* C = (float*)Cp + z * sCz;
        #pragma unroll
        for (int i = 0; i < 4; i++)
            #pragma unroll
            for (int j = 0; j < 4; j++)
                #pragma unroll
                for (int rr = 0; rr < 4; rr++)
                    C[(size_t)(m0 + wm + i * 16 + qd * 4 + rr) * N + (n0 + wn + j * 16 + la)] =
                        acc[i][j][rr];
    }
}

// fused fp32->fp16: blocks [0,4096) convert x (8M), [4096,5632) convert W (3x1M)
__global__ __launch_bounds__(256) void cvt_all(
    const float* __restrict__ x, const float* __restrict__ Wq,
    const float* __restrict__ Wk, const float* __restrict__ Wv,
    _Float16* __restrict__ x_h, _Float16* __restrict__ Wh)
{
    const int bid = blockIdx.x;
    const float* src; _Float16* dst; size_t off;
    if (bid < 4096) {
        src = x; dst = x_h; off = (size_t)bid * 2048;
    } else {
        const int b2 = bid - 4096;
        const int w = b2 >> 9;
        src = (w == 0) ? Wq : ((w == 1) ? Wk : Wv);
        dst = Wh + (size_t)w * 1048576;
        off = (size_t)(b2 & 511) * 2048;
    }
    const size_t i = off + (size_t)threadIdx.x * 8;
    float4 a = *(const float4*)(src + i);
    float4 b = *(const float4*)(src + i + 4);
    h8 o = { (_Float16)a.x, (_Float16)a.y, (_Float16)a.z, (_Float16)a.w,
             (_Float16)b.x, (_Float16)b.y, (_Float16)b.z, (_Float16)b.w };
    *(h8*)(dst + i) = o;
}

// causal row softmax: S fp32 -> P fp16. Thread t owns cols 8t..8t+7.
__global__ __launch_bounds__(256) void softmax_causal(const float* __restrict__ S,
                                                      _Float16* __restrict__ P)
{
    const int idx = blockIdx.x;          // 0..8191
    const int q = idx & 2047;
    const float* Srow = S + (size_t)idx * 2048;
    _Float16* Prow = P + (size_t)idx * 2048;
    const int t = threadIdx.x;
    const int k0 = t * 8;
    const int lane = t & 63, wv = t >> 6;
    __shared__ float red[4];

    float v[8];
    const bool any = (k0 <= q);
    if (any) {
        float4 a = *(const float4*)(Srow + k0);
        float4 b = *(const float4*)(Srow + k0 + 4);
        v[0] = a.x; v[1] = a.y; v[2] = a.z; v[3] = a.w;
        v[4] = b.x; v[5] = b.y; v[6] = b.z; v[7] = b.w;
    }
    float mx = -3.4e38f;
    #pragma unroll
    for (int j = 0; j < 8; j++)
        if (any && k0 + j <= q) mx = fmaxf(mx, v[j]);
    #pragma unroll
    for (int o = 32; o > 0; o >>= 1) mx = fmaxf(mx, __shfl_down(mx, o, 64));
    if (lane == 0) red[wv] = mx;
    __syncthreads();
    const float mall = fmaxf(fmaxf(red[0], red[1]), fmaxf(red[2], red[3]));
    __syncthreads();

    float sum = 0.f;
    #pragma unroll
    for (int j = 0; j < 8; j++) {
        float e = (any && k0 + j <= q) ? __expf(v[j] - mall) : 0.f;
        v[j] = e;
        sum += e;
    }
    #pragma unroll
    for (int o = 32; o > 0; o >>= 1) sum += __shfl_down(sum, o, 64);
    if (lane == 0) red[wv] = sum;
    __syncthreads();
    const float inv = 1.f / (red[0] + red[1] + red[2] + red[3]);

    const int kceil = ((q >> 7) + 1) << 7;       // PV reads cols < kceil
    if (k0 < kceil) {
        h8 o = { (_Float16)(v[0] * inv), (_Float16)(v[1] * inv),
                 (_Float16)(v[2] * inv), (_Float16)(v[3] * inv),
                 (_Float16)(v[4] * inv), (_Float16)(v[5] * inv),
                 (_Float16)(v[6] * inv), (_Float16)(v[7] * inv) };
        *(h8*)(Prow + k0) = o;
    }
}

extern "C" void kernel_launch(void* const* d_in, const int* in_sizes, int n_in,
                              void* d_out, int out_size, void* d_ws, size_t ws_size,
                              hipStream_t stream) {
    const float* x  = (const float*)d_in[0];
    const float* Wq = (const float*)d_in[1];
    const float* Wk = (const float*)d_in[2];
    const float* Wv = (const float*)d_in[3];
    float* out = (float*)d_out;

    const size_t MiB = 1024 * 1024;
    char* ws = (char*)d_ws;
    _Float16* QKVh = (_Float16*)ws;                     // Q,K slabs + Vt at slab 2
    _Float16* Vt   = QKVh + (size_t)2 * 8388608;        // [32,48) MiB, (b,e,s)
    float*    S    = (float*)(ws + 48 * MiB);           // 64 MiB
    _Float16* x_h  = (_Float16*)(ws + 48 * MiB);        // 16 MiB (over S)
    _Float16* Wh   = (_Float16*)(ws + 64 * MiB);        // 6 MiB  (over S)
    _Float16* P    = (_Float16*)ws;                     // 32 MiB (over Q,K)

    const dim3 blk(256);

    // 0) fp32 -> fp16 conversions (one dispatch)
    cvt_all<<<dim3(5632), blk, 0, stream>>>(x, Wq, Wk, Wv, x_h, Wh);

    // 1) QKV fused, 256x192 dense-staged pipeline: M=8192, N=3072
    qkv192<<<dim3(512), dim3(512), 0, stream>>>(x_h, Wh, QKVh);

    // 2) scores: balanced lower-triangle decode, 136 tiles/batch
    gemm_nt<2, 0, false><<<dim3(136, 1, 4), blk, 0, stream>>>(
        QKVh, QKVh + 8388608, S, 2048, 1024,
        (size_t)2097152, (size_t)2097152, (size_t)4194304);

    // 3) causal softmax rows -> P fp16 (over Q,K)
    softmax_causal<<<dim3(4 * 2048), blk, 0, stream>>>(S, P);

    // 4) out = P @ Vt^T, fp32 out, K clipped at m0+128, residue swizzle
    gemm_nt<3, 0, true><<<dim3(128, 1, 4), blk, 0, stream>>>(
        P, Vt, out, 1024, 2048,
        (size_t)4194304, (size_t)2097152, (size_t)2097152);
}

// Round 3
// 232.933 us; speedup vs baseline: 1.0456x; 1.0191x over previous
//
#include <hip/hip_runtime.h>

// ---------------------------------------------------------------------------
// SelfAttention: B=4, S=2048, D=1024, fp32 in/out, causal, no 1/sqrt(d).
// fp16 MFMA (16x16x32), fp32 accumulate, fp32 softmax.
//
// R11 = R10 with the qkv192 fences fixed. R9/R10 wrapped barriers/waits in
// asm volatile("" ::: "memory"); LLVM's waitcnt pass treats memory-clobber
// asm as an unknown memory op and inserts s_waitcnt vmcnt(0) lgkmcnt(0)
// BEFORE it -> every phase drained the global_load_lds queue, the counted
// VMW(4) was dead, and both schedules degenerated to the serial ~31%-util
// structure. Fix (= the verified m201 recipe): raw s_barrier + un-clobbered
// "s_waitcnt vmcnt(N)" asm, ordering pinned by sched_barrier(0) instead of
// memory clobbers. No other change to the pipeline.
//
// ws layout (MiB):
//   [0,32)    Q,K fp16 slabs; later P fp16 overlays (after scores read Q,K)
//   [32,48)   Vt fp16 (b,e,s) — written by QKV epilogue
//   [48,112)  S fp32 (4x2048x2048)
//   [48,64)   x_h fp16      (over S; dead before S written)
//   [64,70)   Wh  fp16 [3072,1024] (over S; dead before S written)
// ---------------------------------------------------------------------------

typedef _Float16 h8 __attribute__((ext_vector_type(8)));
typedef _Float16 h4 __attribute__((ext_vector_type(4)));
typedef float f32x4 __attribute__((ext_vector_type(4)));

#define BM 128
#define BN 128

__device__ __forceinline__ void gl_lds16(const _Float16* g, _Float16* l) {
    __builtin_amdgcn_global_load_lds(
        (const __attribute__((address_space(1))) void*)g,
        (__attribute__((address_space(3))) void*)l, 16, 0, 0);
}

// Fences for the pipelined kernel: NO memory clobbers (they trigger
// conservative vmcnt(0)+lgkmcnt(0) insertion). sched_barrier(0) pins
// instruction order at compile time; s_barrier is the raw HW barrier.
#define SBAR __builtin_amdgcn_sched_barrier(0)
#define BARX do { SBAR; __builtin_amdgcn_s_barrier(); SBAR; } while (0)
#define VMW(n) do { SBAR; asm volatile("s_waitcnt vmcnt(" #n ")"); SBAR; } while (0)

// ---------------------------------------------------------------------------
// qkv192: A = x_h [8192][1024], B = Wh [3072][1024], C = QKV slabs.
// 8 waves 2Mx4N, per-wave 128x48 (8 M-frags x 3 N-frags), acc[8][3].
//
// LDS (halves): Ab0@0 Ab1@16384 Ab2@32768 (each [256][64]);
//               Bb0@49152 Bb1@61440 (each [192][64]). Total 73728 h = 144KB.
// Region layout: row r at r*64, seg s_lds at +s_lds*8; (r,s_lds) holds
// GLOBAL seg s_lds ^ (r&7) (sigma pre-applied at the global source).
// Staging op = 1KB = 8 rows dense: lane l -> row +(l>>3), src seg
// (l&7)^((l>>3)&7) -> each row's 8 lanes cover one dense 128B line.
//
// Window n (4 phases), reads A(n) in Ab[n%3], B(n) in Bb[n%2]:
//   Ph0: bf(s0)+af(h0,s0); stage B(n+1).lo(2)   | BAR; 12 MFMA; BAR
//   Ph1: af(h1,s0);        stage B(n+1).hi(1)   | BAR; 12 MFMA; BAR
//   Ph2: bf(s1)+af(h0,s1); stage A(n+2).lo(2)   | BAR; 12 MFMA; BAR
//   Ph3: af(h1,s1);        stage A(n+2).hi(2)   | BAR; 12 MFMA; VMW(4); BAR
// VMW(4): outstanding = B(n+1).3 + A(n+2).4 (+ A(n+1).4 from prev window,
// already countable-retired) -> forces A(n+1)+B(n+1) (read next window),
// leaves A(n+2) in flight. Never drains to 0 in the main loop.
// ---------------------------------------------------------------------------

#define SA_LO(gp, ab) do { gl_lds16((gp),          (ab) + wv * 1024); \
                           gl_lds16((gp) + 8192,   (ab) + wv * 1024 + 512); } while (0)
#define SA_HI(gp, ab) do { gl_lds16((gp) + 131072, (ab) + wv * 1024 + 8192); \
                           gl_lds16((gp) + 139264, (ab) + wv * 1024 + 8704); } while (0)
#define SB_LO(gp, bb) do { gl_lds16((gp),          (bb) + wv * 1024); \
                           gl_lds16((gp) + 8192,   (bb) + wv * 1024 + 512); } while (0)
#define SB_HI(gp2, bb)     gl_lds16((gp2),         (bb) + 8192 + wv * 512)

#define LDA(ab, h, ap) do { _Pragma("unroll") \
    for (int i = 0; i < 4; i++) \
        af[i] = *(const h8*)&(ab)[abase + (h) * 4096 + i * 1024 + (ap)]; } while (0)
#define LDB(bb, ap) do { _Pragma("unroll") \
    for (int j = 0; j < 3; j++) \
        bf[j] = *(const h8*)&(bb)[bbase + j * 1024 + (ap)]; } while (0)

#define MMP(h) do { __builtin_amdgcn_s_setprio(1); _Pragma("unroll") \
    for (int i = 0; i < 4; i++) { _Pragma("unroll") \
        for (int j = 0; j < 3; j++) \
            acc[(h) * 4 + i][j] = __builtin_amdgcn_mfma_f32_16x16x32_f16( \
                af[i], bf[j], acc[(h) * 4 + i][j], 0, 0, 0); } \
    __builtin_amdgcn_s_setprio(0); } while (0)

__global__ __launch_bounds__(512, 2) void qkv192(
    const _Float16* __restrict__ A, const _Float16* __restrict__ B,
    _Float16* __restrict__ C)
{
    __shared__ __align__(16) _Float16 sm[73728];   // 144 KiB

    // XCD-bijective swizzle (512 % 8 == 0)
    const int bid = blockIdx.x;
    const int wg = (bid & 7) * 64 + (bid >> 3);
    const int by = wg >> 4, bx = wg & 15;
    const int m0 = by * 256, n0 = bx * 192;

    const int tid = threadIdx.x;
    const int l = tid & 63;
    const int wv = tid >> 6;

    // staging addressing: lane l -> row +(l>>3), global seg (l&7)^((l>>3)&7)
    const int prow = wv * 16 + (l >> 3);
    const int pseg = ((l & 7) ^ ((l >> 3) & 7)) * 8;
    const _Float16* gA  = A + (size_t)(m0 + prow) * 1024 + pseg;
    const _Float16* gB  = B + (size_t)(n0 + prow) * 1024 + pseg;
    const _Float16* gB2 = B + (size_t)(n0 + 128 + wv * 8 + (l >> 3)) * 1024 + pseg;

    // fragment addressing
    const int la = l & 15, qd = l >> 4;
    const int wmr = (wv >> 2) * 128;            // 2 M row-groups
    const int wnr = (wv & 3) * 48;              // 4 N col-groups of 48
    const int ap0 = ((qd) ^ (la & 7)) * 8;      // k-step s=0 phys seg
    const int ap1 = ((4 + qd) ^ (la & 7)) * 8;  // k-step s=1 phys seg
    const int abase = (wmr + la) * 64;
    const int bbase = (wnr + la) * 64;

    _Float16* a0 = sm;
    _Float16* a1 = sm + 16384;
    _Float16* a2 = sm + 32768;
    _Float16* b0 = sm + 49152;
    _Float16* b1 = sm + 61440;

    f32x4 acc[8][3];
    #pragma unroll
    for (int i = 0; i < 8; i++)
        #pragma unroll
        for (int j = 0; j < 3; j++)
            acc[i][j] = (f32x4){0.f, 0.f, 0.f, 0.f};

    // prologue: A(0)->Ab0, B(0)->Bb0, A(1)->Ab1 (11 ops); force A(0)+B(0)
    SA_LO(gA, a0);      SA_HI(gA, a0);
    SB_LO(gB, b0);      SB_HI(gB2, b0);
    SA_LO(gA + 64, a1); SA_HI(gA + 64, a1);
    VMW(4);
    BARX;

    const _Float16* pA  = gA + 128;    // k-offset of A(2)
    const _Float16* pB  = gB + 64;     // k-offset of B(1)
    const _Float16* pB2 = gB2 + 64;

    #pragma unroll 1
    for (int n = 0; n < 14; ++n) {
        h8 af[4], bf[3];
        LDB(b0, ap0); LDA(a0, 0, ap0); SB_LO(pB, b1);  BARX; MMP(0); BARX;
        LDA(a0, 1, ap0);               SB_HI(pB2, b1); BARX; MMP(1); BARX;
        LDB(b0, ap1); LDA(a0, 0, ap1); SA_LO(pA, a2);  BARX; MMP(0); BARX;
        LDA(a0, 1, ap1);               SA_HI(pA, a2);  BARX; MMP(1); VMW(4); BARX;
        _Float16* t = a0; a0 = a1; a1 = a2; a2 = t;
        t = b0; b0 = b1; b1 = t;
        pA += 64; pB += 64; pB2 += 64;
    }
    {   // W14: stage only B(15); drain everything at end
        h8 af[4], bf[3];
        LDB(b0, ap0); LDA(a0, 0, ap0); SB_LO(pB, b1);  BARX; MMP(0); BARX;
        LDA(a0, 1, ap0);               SB_HI(pB2, b1); BARX; MMP(1); BARX;
        LDB(b0, ap1); LDA(a0, 0, ap1);                 BARX; MMP(0); BARX;
        LDA(a0, 1, ap1);                               BARX; MMP(1); VMW(0); BARX;
        _Float16* t = a0; a0 = a1; a1 = a2; a2 = t;
        t = b0; b0 = b1; b1 = t;
    }
    {   // W15: reads only
        h8 af[4], bf[3];
        LDB(b0, ap0); LDA(a0, 0, ap0); BARX; MMP(0); BARX;
        LDA(a0, 1, ap0);               BARX; MMP(1); BARX;
        LDB(b0, ap1); LDA(a0, 0, ap1); BARX; MMP(0); BARX;
        LDA(a0, 1, ap1);               BARX; MMP(1);
    }

    // epilogue: D layout col=la, row=qd*4+rr. Slab chosen per 16-aligned
    // frag column (tiles can straddle Q|K|V boundaries since 192∤1024).
    #pragma unroll
    for (int i = 0; i < 8; i++) {
        const int m = m0 + wmr + i * 16 + qd * 4;
        #pragma unroll
        for (int j = 0; j < 3; j++) {
            const int col16 = n0 + wnr + j * 16;
            const int slab = col16 >> 10;
            if (slab < 2) {
                // Q/K slabs, row-major [s][e] within slab, ld 1024
                const size_t base = (size_t)slab * 8388608 + (col16 & 1023) + la;
                #pragma unroll
                for (int rr = 0; rr < 4; rr++)
                    C[base + (size_t)(m + rr) * 1024] = (_Float16)acc[i][j][rr];
            } else {
                // V slab stored transposed: Vt (b, e, s); rr -> s contiguous
                _Float16* Vt = C + (size_t)2 * 8388608;
                const int e = col16 + la - 2048;
                const int b = m >> 11;
                const int sl = m & 2047;
                h4 vv = { (_Float16)acc[i][j][0], (_Float16)acc[i][j][1],
                          (_Float16)acc[i][j][2], (_Float16)acc[i][j][3] };
                *(h4*)(Vt + (size_t)b * 2097152 + (size_t)e * 2048 + sl) = vv;
            }
        }
    }
}

// ---------------------------------------------------------------------------
// NT GEMM (R8 structure) kept for scores (SWZ=2) and PV (SWZ=3).
// ---------------------------------------------------------------------------
template<int SWZ, int OM, bool KLIM>
__global__ __launch_bounds__(256) void gemm_nt(
    const _Float16* __restrict__ A, const _Float16* __restrict__ B,
    void* __restrict__ Cp, int N, int K,
    size_t sAz, size_t sBz, size_t sCz)
{
    __shared__ __align__(16) char smem[32768];
    _Float16* As = (_Float16*)smem;              // 2 x 4096 halves (k-stages)
    _Float16* Bs = (_Float16*)(smem + 16384);    // 2 x 4096 halves

    int bx, by;
    if (SWZ == 1) {
        const int r = blockIdx.x & 7, q2 = blockIdx.x >> 3;
        bx = q2 >> 3;
        by = ((q2 & 7) << 3) | r;
    } else if (SWZ == 2) {
        const int r = blockIdx.x & 7, g = blockIdx.x >> 3;   // g in 0..16
        if (g <= r) { by = r;      bx = g; }
        else        { by = 15 - r; bx = g - (r + 1); }
    } else {                                      // SWZ == 3
        const int r = blockIdx.x & 7, g = blockIdx.x >> 3;   // g in 0..15
        by = (g & 1) ? (15 - r) : r;
        bx = g >> 1;
    }

    const int tid  = threadIdx.x;
    const int lane = tid & 63;
    const int wv   = tid >> 6;
    const int m0 = by * BM, n0 = bx * BN;
    const size_t z = blockIdx.z;

    const int lr = lane >> 2;
    const int lc = ((lane & 3) ^ ((lane >> 3) & 3)) * 8;
    const _Float16* pA0 = A + z * sAz + (size_t)(m0 + wv * 16 + lr) * K + lc;
    const _Float16* pA1 = pA0 + (size_t)64 * K;
    const _Float16* pB0 = B + z * sBz + (size_t)(n0 + wv * 16 + lr) * K + lc;
    const _Float16* pB1 = pB0 + (size_t)64 * K;
    _Float16* lA0 = As + wv * 512;
    _Float16* lA1 = As + (wv + 4) * 512;
    _Float16* lB0 = Bs + wv * 512;
    _Float16* lB1 = Bs + (wv + 4) * 512;

    const int la = lane & 15;
    const int qd = lane >> 4;
    const int wm = (wv >> 1) * 64;
    const int wn = (wv & 1) * 64;
    const int sg = (qd ^ ((la >> 1) & 3)) * 8;

    f32x4 acc[4][4];
    #pragma unroll
    for (int i = 0; i < 4; i++)
        #pragma unroll
        for (int j = 0; j < 4; j++)
            acc[i][j] = (f32x4){0.f, 0.f, 0.f, 0.f};

    const int kEnd = KLIM ? (m0 + BM) : K;

    for (int k0 = 0; k0 < kEnd; k0 += 64) {
        gl_lds16(pA0,      lA0);
        gl_lds16(pA1,      lA1);
        gl_lds16(pB0,      lB0);
        gl_lds16(pB1,      lB1);
        gl_lds16(pA0 + 32, lA0 + 4096);
        gl_lds16(pA1 + 32, lA1 + 4096);
        gl_lds16(pB0 + 32, lB0 + 4096);
        gl_lds16(pB1 + 32, lB1 + 4096);
        pA0 += 64; pA1 += 64; pB0 += 64; pB1 += 64;
        __syncthreads();

        #pragma unroll
        for (int s = 0; s < 2; s++) {
            h8 af[4], bf[4];
            #pragma unroll
            for (int i = 0; i < 4; i++)
                af[i] = *(const h8*)&As[s * 4096 + (wm + i * 16 + la) * 32 + sg];
            #pragma unroll
            for (int i = 0; i < 4; i++)
                bf[i] = *(const h8*)&Bs[s * 4096 + (wn + i * 16 + la) * 32 + sg];
            #pragma unroll
            for (int i = 0; i < 4; i++)
                #pragma unroll
                for (int j = 0; j < 4; j++)
                    acc[i][j] = __builtin_amdgcn_mfma_f32_16x16x32_f16(af[i], bf[j], acc[i][j], 0, 0, 0);
        }
        __syncthreads();
    }

    if (OM == 2) {
        _Float16* C = (_Float16*)Cp;
        if (n0 < 2048) {
            #pragma unroll
            for (int i = 0; i < 4; i++)
                #pragma unroll
                for (int j = 0; j < 4; j++) {
                    const int col  = n0 + wn + j * 16 + la;
                    const size_t base = (size_t)(col >> 10) * 8388608 + (col & 1023);
                    #pragma unroll
                    for (int rr = 0; rr < 4; rr++)
                        C[base + (size_t)(m0 + wm + i * 16 + qd * 4 + rr) * 1024] =
                            (_Float16)acc[i][j][rr];
                }
        } else {
            _Float16* Vt = C + (size_t)2 * 8388608;
            #pragma unroll
            for (int i = 0; i < 4; i++) {
                const int m  = m0 + wm + i * 16 + qd * 4;
                const int b  = m >> 11;
                const int sl = m & 2047;
                _Float16* Vb = Vt + (size_t)b * 2097152 + sl;
                #pragma unroll
                for (int j = 0; j < 4; j++) {
                    const int e = n0 - 2048 + wn + j * 16 + la;
                    h4 vv = { (_Float16)acc[i][j][0], (_Float16)acc[i][j][1],
                              (_Float16)acc[i][j][2], (_Float16)acc[i][j][3] };
                    *(h4*)(Vb + (size_t)e * 2048) = vv;
                }
            }
        }
    } else {
        float* C = (float*)Cp + z * sCz;
        #pragma unroll
        for (int i = 0; i < 4; i++)
            #pragma unroll
            for (int j = 0; j < 4; j++)
                #pragma unroll
                for (int rr = 0; rr < 4; rr++)
                    C[(size_t)(m0 + wm + i * 16 + qd * 4 + rr) * N + (n0 + wn + j * 16 + la)] =
                        acc[i][j][rr];
    }
}

// fused fp32->fp16: blocks [0,4096) convert x (8M), [4096,5632) convert W (3x1M)
__global__ __launch_bounds__(256) void cvt_all(
    const float* __restrict__ x, const float* __restrict__ Wq,
    const float* __restrict__ Wk, const float* __restrict__ Wv,
    _Float16* __restrict__ x_h, _Float16* __restrict__ Wh)
{
    const int bid = blockIdx.x;
    const float* src; _Float16* dst; size_t off;
    if (bid < 4096) {
        src = x; dst = x_h; off = (size_t)bid * 2048;
    } else {
        const int b2 = bid - 4096;
        const int w = b2 >> 9;
        src = (w == 0) ? Wq : ((w == 1) ? Wk : Wv);
        dst = Wh + (size_t)w * 1048576;
        off = (size_t)(b2 & 511) * 2048;
    }
    const size_t i = off + (size_t)threadIdx.x * 8;
    float4 a = *(const float4*)(src + i);
    float4 b = *(const float4*)(src + i + 4);
    h8 o = { (_Float16)a.x, (_Float16)a.y, (_Float16)a.z, (_Float16)a.w,
             (_Float16)b.x, (_Float16)b.y, (_Float16)b.z, (_Float16)b.w };
    *(h8*)(dst + i) = o;
}

// causal row softmax: S fp32 -> P fp16. Thread t owns cols 8t..8t+7.
__global__ __launch_bounds__(256) void softmax_causal(const float* __restrict__ S,
                                                      _Float16* __restrict__ P)
{
    const int idx = blockIdx.x;          // 0..8191
    const int q = idx & 2047;
    const float* Srow = S + (size_t)idx * 2048;
    _Float16* Prow = P + (size_t)idx * 2048;
    const int t = threadIdx.x;
    const int k0 = t * 8;
    const int lane = t & 63, wv = t >> 6;
    __shared__ float red[4];

    float v[8];
    const bool any = (k0 <= q);
    if (any) {
        float4 a = *(const float4*)(Srow + k0);
        float4 b = *(const float4*)(Srow + k0 + 4);
        v[0] = a.x; v[1] = a.y; v[2] = a.z; v[3] = a.w;
        v[4] = b.x; v[5] = b.y; v[6] = b.z; v[7] = b.w;
    }
    float mx = -3.4e38f;
    #pragma unroll
    for (int j = 0; j < 8; j++)
        if (any && k0 + j <= q) mx = fmaxf(mx, v[j]);
    #pragma unroll
    for (int o = 32; o > 0; o >>= 1) mx = fmaxf(mx, __shfl_down(mx, o, 64));
    if (lane == 0) red[wv] = mx;
    __syncthreads();
    const float mall = fmaxf(fmaxf(red[0], red[1]), fmaxf(red[2], red[3]));
    __syncthreads();

    float sum = 0.f;
    #pragma unroll
    for (int j = 0; j < 8; j++) {
        float e = (any && k0 + j <= q) ? __expf(v[j] - mall) : 0.f;
        v[j] = e;
        sum += e;
    }
    #pragma unroll
    for (int o = 32; o > 0; o >>= 1) sum += __shfl_down(sum, o, 64);
    if (lane == 0) red[wv] = sum;
    __syncthreads();
    const float inv = 1.f / (red[0] + red[1] + red[2] + red[3]);

    const int kceil = ((q >> 7) + 1) << 7;       // PV reads cols < kceil
    if (k0 < kceil) {
        h8 o = { (_Float16)(v[0] * inv), (_Float16)(v[1] * inv),
                 (_Float16)(v[2] * inv), (_Float16)(v[3] * inv),
                 (_Float16)(v[4] * inv), (_Float16)(v[5] * inv),
                 (_Float16)(v[6] * inv), (_Float16)(v[7] * inv) };
        *(h8*)(Prow + k0) = o;
    }
}

extern "C" void kernel_launch(void* const* d_in, const int* in_sizes, int n_in,
                              void* d_out, int out_size, void* d_ws, size_t ws_size,
                              hipStream_t stream) {
    const float* x  = (const float*)d_in[0];
    const float* Wq = (const float*)d_in[1];
    const float* Wk = (const float*)d_in[2];
    const float* Wv = (const float*)d_in[3];
    float* out = (float*)d_out;

    const size_t MiB = 1024 * 1024;
    char* ws = (char*)d_ws;
    _Float16* QKVh = (_Float16*)ws;                     // Q,K slabs + Vt at slab 2
    _Float16* Vt   = QKVh + (size_t)2 * 8388608;        // [32,48) MiB, (b,e,s)
    float*    S    = (float*)(ws + 48 * MiB);           // 64 MiB
    _Float16* x_h  = (_Float16*)(ws + 48 * MiB);        // 16 MiB (over S)
    _Float16* Wh   = (_Float16*)(ws + 64 * MiB);        // 6 MiB  (over S)
    _Float16* P    = (_Float16*)ws;                     // 32 MiB (over Q,K)

    const dim3 blk(256);

    // 0) fp32 -> fp16 conversions (one dispatch)
    cvt_all<<<dim3(5632), blk, 0, stream>>>(x, Wq, Wk, Wv, x_h, Wh);

    // 1) QKV fused, 256x192 dense-staged pipeline: M=8192, N=3072
    qkv192<<<dim3(512), dim3(512), 0, stream>>>(x_h, Wh, QKVh);

    // 2) scores: balanced lower-triangle decode, 136 tiles/batch
    gemm_nt<2, 0, false><<<dim3(136, 1, 4), blk, 0, stream>>>(
        QKVh, QKVh + 8388608, S, 2048, 1024,
        (size_t)2097152, (size_t)2097152, (size_t)4194304);

    // 3) causal softmax rows -> P fp16 (over Q,K)
    softmax_causal<<<dim3(4 * 2048), blk, 0, stream>>>(S, P);

    // 4) out = P @ Vt^T, fp32 out, K clipped at m0+128, residue swizzle
    gemm_nt<3, 0, true><<<dim3(128, 1, 4), blk, 0, stream>>>(
        P, Vt, out, 1024, 2048,
        (size_t)4194304, (size_t)2097152, (size_t)2097152);
}